// Round 5
// baseline (89.657 us; speedup 1.0000x reference)
//
#include <hip/hip_runtime.h>
#include <math.h>

#define S_LEN  2048
#define D_HEAD 128
#define QBLK   64
#define KVBLK  64
#define NWAVES 4
#define BATCH  16
#define NKVT   (S_LEN / KVBLK)     // 32 kv tiles per batch
#define TILE_SH 8192               // shorts per 64x128 tile image (16 KB)

typedef __attribute__((ext_vector_type(4))) float f32x4;
typedef __attribute__((ext_vector_type(8))) short short8;

__device__ __forceinline__ unsigned short f2bf(float x) {
    union { float f; unsigned u; } v; v.f = x;
    unsigned r = v.u + 0x7fffu + ((v.u >> 16) & 1u);
    return (unsigned short)(r >> 16);
}
__device__ __forceinline__ unsigned pack2(unsigned short a, unsigned short b) {
    return (unsigned)a | ((unsigned)b << 16);
}
__device__ __forceinline__ unsigned cvtpk(float lo, float hi) {
    unsigned r;
    asm("v_cvt_pk_bf16_f32 %0, %1, %2" : "=v"(r) : "v"(lo), "v"(hi));
    return r;
}
__device__ __forceinline__ void gld16(const void* g, void* l) {
    __builtin_amdgcn_global_load_lds(
        (const __attribute__((address_space(1))) void*)g,
        (__attribute__((address_space(3))) void*)l, 16, 0, 0);
}

// prep: one block per (batch, kv-tile). Emits PRE-SWIZZLED contiguous LDS images.
__global__ __launch_bounds__(256) void prep(const float* __restrict__ K,
                                            const float* __restrict__ V,
                                            unsigned short* __restrict__ Kp,
                                            unsigned short* __restrict__ Vp)
{
    const int tid = threadIdx.x;
    const int bid = blockIdx.x;
    const int b = bid >> 5, t = bid & 31;
    const size_t ibase = (size_t)b * S_LEN * D_HEAD + (size_t)t * KVBLK * D_HEAD;
    unsigned short* ko = Kp + (size_t)bid * TILE_SH;
    unsigned short* vo = Vp + (size_t)bid * TILE_SH;

    #pragma unroll
    for (int c = 0; c < 4; ++c) {
        int i  = c * 256 + tid;
        int k  = i >> 4;
        int d8 = ((i & 15) * 8) ^ ((k & 7) << 3);
        const float* sp = K + ibase + (size_t)k * D_HEAD + d8;
        float4 a = *(const float4*)sp;
        float4 bb = *(const float4*)(sp + 4);
        uint4 u = { pack2(f2bf(a.x),f2bf(a.y)),  pack2(f2bf(a.z),f2bf(a.w)),
                    pack2(f2bf(bb.x),f2bf(bb.y)),pack2(f2bf(bb.z),f2bf(bb.w)) };
        *(uint4*)(ko + i * 8) = u;
    }

    __shared__ unsigned short Vb[KVBLK][D_HEAD + 2];
    {
        const int r  = tid >> 2;
        const int c0 = (tid & 3) * 32;
        const float* sp = V + ibase + (size_t)r * D_HEAD + c0;
        #pragma unroll
        for (int i = 0; i < 8; ++i) {
            float4 x = *(const float4*)(sp + i * 4);
            Vb[r][c0+i*4+0] = f2bf(x.x); Vb[r][c0+i*4+1] = f2bf(x.y);
            Vb[r][c0+i*4+2] = f2bf(x.z); Vb[r][c0+i*4+3] = f2bf(x.w);
        }
    }
    __syncthreads();
    #pragma unroll
    for (int c = 0; c < 4; ++c) {
        int i   = c * 256 + tid;
        int d   = i >> 3;
        int kk0 = ((i & 7) * 8) ^ ((d & 7) << 3);
        unsigned short h[8];
        #pragma unroll
        for (int j = 0; j < 8; ++j) h[j] = Vb[kk0 + j][d];
        uint4 u = { pack2(h[0],h[1]), pack2(h[2],h[3]), pack2(h[4],h[5]), pack2(h[6],h[7]) };
        *(uint4*)(vo + i * 8) = u;
    }
}

// MODE 0: 512 blocks, complementary pairing, direct O.
// MODE 1: 768 blocks. bid<512: heavy halves (qb 16..31, kv range split), fp32 partials.
//         bid>=512: light (qb 0..15), direct O.
template<int MODE>
__global__ __launch_bounds__(256, 2)
void attn_fwd(const float* __restrict__ Qg, const unsigned short* __restrict__ Kp,
              const unsigned short* __restrict__ Vp, float* __restrict__ Og,
              float* __restrict__ Po, float* __restrict__ Ml)
{
    constexpr float CSC = 0.12751744f;      // log2(e)/sqrt(128), folded into Q
    const int tid  = threadIdx.x;
    const int lane = tid & 63;
    const int w    = tid >> 6;
    const int bid  = blockIdx.x;

    int b, qb, lo_t, hi_t, pslot = -1;
    if (MODE == 0) {
        b = bid & 15;
        const int rank = bid >> 4;
        qb = (rank < 16) ? (31 - rank) : (rank - 16);
        lo_t = 0; hi_t = qb + 1;
    } else {
        if (bid < 512) {
            b  = bid >> 5;
            qb = 31 - (bid & 15);
            const int half = (bid >> 4) & 1;
            const int h = (qb + 1) >> 1;
            lo_t = half ? h : 0;
            hi_t = half ? (qb + 1) : h;
            pslot = ((b << 4) | (qb - 16)) * 2 + half;
        } else {
            const int idx = bid - 512;
            b  = idx >> 4;
            qb = 15 - (idx & 15);
            lo_t = 0; hi_t = qb + 1;
        }
    }
    const int q0   = qb * QBLK;
    const int q0w  = q0 + w * 16;
    const int qc   = lane & 15;
    const int g    = lane >> 4;

    __shared__ __align__(16) unsigned short Klds[2][TILE_SH];
    __shared__ __align__(16) unsigned short Vlds[2][TILE_SH];
    __shared__ __align__(16) unsigned short Plds[NWAVES][16 * KVBLK];

    const size_t base = (size_t)b * S_LEN * D_HEAD;

    // ---- Q fragments (MFMA B operand), pre-scaled ----
    short8 qf[4];
    {
        const float* qp = Qg + base + (size_t)(q0w + qc) * D_HEAD + g * 8;
        #pragma unroll
        for (int db = 0; db < 4; ++db) {
            float4 x0 = *(const float4*)(qp + db * 32);
            float4 x1 = *(const float4*)(qp + db * 32 + 4);
            float tt[8] = {x0.x, x0.y, x0.z, x0.w, x1.x, x1.y, x1.z, x1.w};
            short8 f;
            #pragma unroll
            for (int j = 0; j < 8; ++j) f[j] = (short)f2bf(tt[j] * CSC);
            qf[db] = f;
        }
    }

    const int tb = b * NKVT;
    auto stage = [&](int t, int dst) {
        const unsigned short* ks = Kp + (size_t)(tb + t) * TILE_SH + w * 2048 + lane * 8;
        const unsigned short* vs = Vp + (size_t)(tb + t) * TILE_SH + w * 2048 + lane * 8;
        unsigned short* kd = &Klds[dst][w * 2048];
        unsigned short* vd = &Vlds[dst][w * 2048];
        #pragma unroll
        for (int i = 0; i < 4; ++i) {
            gld16(ks + i * 512, kd + i * 512);
            gld16(vs + i * 512, vd + i * 512);
        }
    };

    f32x4 o[8] = {};                        // o[db][r] = O[q=4g+r][d=db*16+qc]
    float m = -1e30f, lsum = 0.f;           // lsum stays LANE-PARTIAL (reduced in epilogue)
    const int qidx = q0w + qc;
    const int nt = hi_t - lo_t;

    stage(lo_t, 0);
    __syncthreads();

    for (int i = 0; i < nt; ++i) {
        const int buf = i & 1;
        const int kv0 = (lo_t + i) * KVBLK;
        if (i + 1 < nt) stage(lo_t + i + 1, buf ^ 1);

        // fully-masked subtile skip (uniform formula; 3 / 1 off-diagonal)
        const int t16max = min(3, (q0w + 15 - kv0) >> 4);
        const int ksmax  = min(1, (q0w + 15 - kv0) >> 5);

        // ---- swapped QK^T: rows = k, cols = q ----
        f32x4 st[4] = {};
        __builtin_amdgcn_s_setprio(1);
        #pragma unroll
        for (int t16 = 0; t16 < 4; ++t16) {
            if (t16 <= t16max) {
                const int kr = t16 * 16 + qc;
                const int swz = (kr & 7) << 3;
                #pragma unroll
                for (int db = 0; db < 4; ++db) {
                    short8 kf = *(const short8*)&Klds[buf][(kr * 128 + db * 32 + g * 8) ^ swz];
                    st[t16] = __builtin_amdgcn_mfma_f32_16x16x32_bf16(kf, qf[db], st[t16], 0, 0, 0);
                }
            }
        }
        __builtin_amdgcn_s_setprio(0);

        float s[16];
        #pragma unroll
        for (int t16 = 0; t16 < 4; ++t16)
            #pragma unroll
            for (int r = 0; r < 4; ++r)
                s[t16*4+r] = (t16 <= t16max) ? st[t16][r] : -1e30f;

        if (kv0 + KVBLK - 1 > q0w) {        // diagonal: per-lane causal mask
            #pragma unroll
            for (int t16 = 0; t16 < 4; ++t16)
                #pragma unroll
                for (int r = 0; r < 4; ++r)
                    if (kv0 + t16 * 16 + g * 4 + r > qidx) s[t16*4+r] = -1e30f;
        }

        // ---- online softmax, defer-max; NO cross-lane ops in common path ----
        float m0 = fmaxf(fmaxf(s[0],s[1]), fmaxf(s[2],s[3]));
        float m1 = fmaxf(fmaxf(s[4],s[5]), fmaxf(s[6],s[7]));
        float m2 = fmaxf(fmaxf(s[8],s[9]), fmaxf(s[10],s[11]));
        float m3 = fmaxf(fmaxf(s[12],s[13]), fmaxf(s[14],s[15]));
        float mx = fmaxf(fmaxf(m0,m1), fmaxf(m2,m3));   // lane-local max

        if (__any(mx > m + 8.0f)) {         // rescale only when some row max grew > THR
            mx = fmaxf(mx, __shfl_xor(mx, 16));
            mx = fmaxf(mx, __shfl_xor(mx, 32));         // row max (only when needed)
            float mnew = fmaxf(m, mx);
            float alpha = exp2f(m - mnew);
            m = mnew;
            lsum *= alpha;
            float a_o[4];
            #pragma unroll
            for (int r = 0; r < 4; ++r) a_o[r] = __shfl(alpha, g * 4 + r);
            #pragma unroll
            for (int db = 0; db < 8; ++db)
                #pragma unroll
                for (int r = 0; r < 4; ++r) o[db][r] *= a_o[r];
        }

        float p[16];
        #pragma unroll
        for (int ii = 0; ii < 16; ++ii) p[ii] = exp2f(s[ii] - m);
        float r0 = (p[0]+p[1]) + (p[2]+p[3]);
        float r1 = (p[4]+p[5]) + (p[6]+p[7]);
        float r2 = (p[8]+p[9]) + (p[10]+p[11]);
        float r3 = (p[12]+p[13]) + (p[14]+p[15]);
        lsum += (r0+r1) + (r2+r3);          // lane-partial

        // ---- P -> wave-private LDS (bf16, swizzled) ----
        const int pswz = (qc & 7) << 3;
        #pragma unroll
        for (int t16 = 0; t16 < 4; ++t16) {
            uint2 u = { cvtpk(p[t16*4+0], p[t16*4+1]), cvtpk(p[t16*4+2], p[t16*4+3]) };
            *(uint2*)&Plds[w][(qc * 64 + t16 * 16 + g * 4) ^ pswz] = u;
        }

        // ---- PV ----
        __builtin_amdgcn_s_setprio(1);
        #pragma unroll
        for (int ks = 0; ks < 2; ++ks) {
            if (ks <= ksmax) {
                short8 pa = *(const short8*)&Plds[w][(qc * 64 + ks * 32 + g * 8) ^ pswz];
                #pragma unroll
                for (int db = 0; db < 8; ++db) {
                    const int d = db * 16 + qc;
                    short8 vf = *(const short8*)&Vlds[buf][(d * 64 + ks * 32 + g * 8) ^ ((d & 7) << 3)];
                    o[db] = __builtin_amdgcn_mfma_f32_16x16x32_bf16(pa, vf, o[db], 0, 0, 0);
                }
            }
        }
        __builtin_amdgcn_s_setprio(0);

        __syncthreads();
    }

    // ---- epilogue: reduce lane-partial lsum across the 4 row-lanes ----
    lsum += __shfl_xor(lsum, 16);
    lsum += __shfl_xor(lsum, 32);

    if (MODE == 1 && pslot >= 0) {
        // fp32 partials: unnormalized o + per-row (m, l).  Row = w*16 + g*4 + r !
        float* po = Po + (size_t)pslot * (QBLK * D_HEAD);
        #pragma unroll
        for (int db = 0; db < 8; ++db)
            #pragma unroll
            for (int r = 0; r < 4; ++r)
                po[(w * 16 + g * 4 + r) * D_HEAD + db * 16 + qc] = o[db][r];
        if (g == 0) {                        // lanes 0..15 cover this wave's 16 rows
            float* ml = Ml + (size_t)pslot * (QBLK * 2);
            ml[(w * 16 + qc) * 2 + 0] = m;
            ml[(w * 16 + qc) * 2 + 1] = lsum;
        }
    } else {
        float linv = 1.0f / lsum;
        float li[4];
        #pragma unroll
        for (int r = 0; r < 4; ++r) li[r] = __shfl(linv, g * 4 + r);
        #pragma unroll
        for (int db = 0; db < 8; ++db)
            #pragma unroll
            for (int r = 0; r < 4; ++r)
                Og[base + (size_t)(q0w + g * 4 + r) * D_HEAD + db * 16 + qc] = o[db][r] * li[r];
    }
}

// combine two KV-halves of each heavy q-block
__global__ __launch_bounds__(256)
void combine(const float* __restrict__ Po, const float* __restrict__ Ml,
             float* __restrict__ Og)
{
    const int hq  = blockIdx.x;             // 0..255
    const int tid = threadIdx.x;
    const int b   = hq >> 4;
    const int qb  = 16 + (hq & 15);
    const int row = tid >> 2;
    const int c0  = (tid & 3) * 32;

    const float* mlA = Ml + (size_t)(hq * 2 + 0) * (QBLK * 2);
    const float* mlB = Ml + (size_t)(hq * 2 + 1) * (QBLK * 2);
    const float mA = mlA[row*2], lA = mlA[row*2+1];
    const float mB = mlB[row*2], lB = mlB[row*2+1];
    const float M  = fmaxf(mA, mB);
    const float aA = exp2f(mA - M), aB = exp2f(mB - M);
    const float rdenom = 1.0f / (aA * lA + aB * lB);

    const float* pA = Po + (size_t)(hq * 2 + 0) * (QBLK * D_HEAD) + row * D_HEAD + c0;
    const float* pB = Po + (size_t)(hq * 2 + 1) * (QBLK * D_HEAD) + row * D_HEAD + c0;
    float* op = Og + (size_t)b * S_LEN * D_HEAD + (size_t)(qb * QBLK + row) * D_HEAD + c0;

    #pragma unroll
    for (int j = 0; j < 8; ++j) {
        float4 xa = *(const float4*)(pA + j * 4);
        float4 xb = *(const float4*)(pB + j * 4);
        float4 r;
        r.x = (aA*xa.x + aB*xb.x) * rdenom;
        r.y = (aA*xa.y + aB*xb.y) * rdenom;
        r.z = (aA*xa.z + aB*xb.z) * rdenom;
        r.w = (aA*xa.w + aB*xb.w) * rdenom;
        *(float4*)(op + j * 4) = r;
    }
}

extern "C" void kernel_launch(void* const* d_in, const int* in_sizes, int n_in,
                              void* d_out, int out_size, void* d_ws, size_t ws_size,
                              hipStream_t stream) {
    const float* Q = (const float*)d_in[0];
    const float* K = (const float*)d_in[1];
    const float* V = (const float*)d_in[2];
    float* O = (float*)d_out;

    const size_t tile_elems = (size_t)BATCH * NKVT * TILE_SH;   // 4,194,304 shorts
    unsigned short* Kp = (unsigned short*)d_ws;
    unsigned short* Vp = Kp + tile_elems;
    float*          Po = (float*)(Vp + tile_elems);             // 512 * 8192 floats
    float*          Mlp = Po + (size_t)512 * QBLK * D_HEAD;
    const size_t need_bytes = (char*)(Mlp + 512 * QBLK * 2) - (char*)d_ws;

    prep<<<dim3(BATCH * NKVT), dim3(256), 0, stream>>>(K, V, Kp, Vp);
    if (ws_size >= need_bytes) {
        attn_fwd<1><<<dim3(768), dim3(256), 0, stream>>>(Q, Kp, Vp, O, Po, Mlp);
        combine<<<dim3(256), dim3(256), 0, stream>>>(Po, Mlp, O);
    } else {
        attn_fwd<0><<<dim3(512), dim3(256), 0, stream>>>(Q, Kp, Vp, O, nullptr, nullptr);
    }
}

// Round 6
// 64.153 us; speedup vs baseline: 1.3976x; 1.3976x over previous
//
#include <hip/hip_runtime.h>
#include <math.h>

#define S_LEN  2048
#define D_HEAD 128
#define QBLK   64
#define KVBLK  64
#define NWAVES 4
#define BATCH  16
#define NKVT   (S_LEN / KVBLK)     // 32 kv tiles per batch
#define TILE_SH 8192               // shorts per 64x128 tile image (16 KB)

typedef __attribute__((ext_vector_type(4))) float f32x4;
typedef __attribute__((ext_vector_type(8))) short short8;

__device__ __forceinline__ unsigned short f2bf(float x) {
    union { float f; unsigned u; } v; v.f = x;
    unsigned r = v.u + 0x7fffu + ((v.u >> 16) & 1u);
    return (unsigned short)(r >> 16);
}
__device__ __forceinline__ unsigned pack2(unsigned short a, unsigned short b) {
    return (unsigned)a | ((unsigned)b << 16);
}
__device__ __forceinline__ unsigned cvtpk(float lo, float hi) {
    unsigned r;
    asm("v_cvt_pk_bf16_f32 %0, %1, %2" : "=v"(r) : "v"(lo), "v"(hi));
    return r;
}
__device__ __forceinline__ void gld16(const void* g, void* l) {
    __builtin_amdgcn_global_load_lds(
        (const __attribute__((address_space(1))) void*)g,
        (__attribute__((address_space(3))) void*)l, 16, 0, 0);
}
template<int N> __device__ __forceinline__ void wait_vm() {
    asm volatile("s_waitcnt vmcnt(%0)" :: "i"(N) : "memory");
}
__device__ __forceinline__ void barrier() {
    __builtin_amdgcn_sched_barrier(0);
    __builtin_amdgcn_s_barrier();
    __builtin_amdgcn_sched_barrier(0);
}

// prep: one block per (batch, kv-tile). Emits PRE-SWIZZLED contiguous LDS images.
__global__ __launch_bounds__(256) void prep(const float* __restrict__ K,
                                            const float* __restrict__ V,
                                            unsigned short* __restrict__ Kp,
                                            unsigned short* __restrict__ Vp)
{
    const int tid = threadIdx.x;
    const int bid = blockIdx.x;
    const int b = bid >> 5, t = bid & 31;
    const size_t ibase = (size_t)b * S_LEN * D_HEAD + (size_t)t * KVBLK * D_HEAD;
    unsigned short* ko = Kp + (size_t)bid * TILE_SH;
    unsigned short* vo = Vp + (size_t)bid * TILE_SH;

    #pragma unroll
    for (int c = 0; c < 4; ++c) {
        int i  = c * 256 + tid;
        int k  = i >> 4;
        int d8 = ((i & 15) * 8) ^ ((k & 7) << 3);
        const float* sp = K + ibase + (size_t)k * D_HEAD + d8;
        float4 a = *(const float4*)sp;
        float4 bb = *(const float4*)(sp + 4);
        uint4 u = { pack2(f2bf(a.x),f2bf(a.y)),  pack2(f2bf(a.z),f2bf(a.w)),
                    pack2(f2bf(bb.x),f2bf(bb.y)),pack2(f2bf(bb.z),f2bf(bb.w)) };
        *(uint4*)(ko + i * 8) = u;
    }

    __shared__ unsigned short Vb[KVBLK][D_HEAD + 2];
    {
        const int r  = tid >> 2;
        const int c0 = (tid & 3) * 32;
        const float* sp = V + ibase + (size_t)r * D_HEAD + c0;
        #pragma unroll
        for (int i = 0; i < 8; ++i) {
            float4 x = *(const float4*)(sp + i * 4);
            Vb[r][c0+i*4+0] = f2bf(x.x); Vb[r][c0+i*4+1] = f2bf(x.y);
            Vb[r][c0+i*4+2] = f2bf(x.z); Vb[r][c0+i*4+3] = f2bf(x.w);
        }
    }
    __syncthreads();
    #pragma unroll
    for (int c = 0; c < 4; ++c) {
        int i   = c * 256 + tid;
        int d   = i >> 3;
        int kk0 = ((i & 7) * 8) ^ ((d & 7) << 3);
        unsigned short h[8];
        #pragma unroll
        for (int j = 0; j < 8; ++j) h[j] = Vb[kk0 + j][d];
        uint4 u = { pack2(h[0],h[1]), pack2(h[2],h[3]), pack2(h[4],h[5]), pack2(h[6],h[7]) };
        *(uint4*)(vo + i * 8) = u;
    }
}

// MODE 0 (fallback): 512 blocks, complementary pairing, direct O.
// MODE 1: 768 blocks in 3 rounds of 256. CU (x,i) gets a balanced triple:
//   r=0: qb=16+a half0  (partial out)   r=1: qb=16+a half1 (partial out)
//   r=2: qb=15-a full   (direct out)    where b = 2x + (i>>4), a = i&15.
template<int MODE>
__global__ __launch_bounds__(256, 4)
void attn_fwd(const float* __restrict__ Qg, const unsigned short* __restrict__ Kp,
              const unsigned short* __restrict__ Vp, float* __restrict__ Og,
              float* __restrict__ Po, float* __restrict__ Ml)
{
    constexpr float CSC = 0.12751744f;      // log2(e)/sqrt(128), folded into Q
    const int tid  = threadIdx.x;
    const int lane = tid & 63;
    const int w    = tid >> 6;
    const int bid  = blockIdx.x;

    int b, qb, lo_t, hi_t, pslot = -1;
    if (MODE == 0) {
        b = bid & 15;
        const int rank = bid >> 4;
        qb = (rank < 16) ? (31 - rank) : (rank - 16);
        lo_t = 0; hi_t = qb + 1;
    } else {
        const int r = bid >> 8;             // round 0..2
        const int x = bid & 7;              // XCD
        const int i = (bid >> 3) & 31;      // CU index within XCD
        b = 2 * x + (i >> 4);
        const int a = i & 15;
        if (r < 2) {
            qb = 16 + a;
            const int h = (qb + 2) >> 1;    // ceil((qb+1)/2)
            lo_t = r ? h : 0;
            hi_t = r ? (qb + 1) : h;
            pslot = ((b << 4) | a) * 2 + r;
        } else {
            qb = 15 - a;
            lo_t = 0; hi_t = qb + 1;
        }
    }
    const int q0   = qb * QBLK;
    const int q0w  = q0 + w * 16;
    const int qc   = lane & 15;
    const int g    = lane >> 4;

    __shared__ __align__(16) unsigned short Klds[TILE_SH];            // 16 KB
    __shared__ __align__(16) unsigned short Vlds[TILE_SH];            // 16 KB
    __shared__ __align__(16) unsigned short Plds[NWAVES][16 * KVBLK]; //  8 KB

    const size_t base = (size_t)b * S_LEN * D_HEAD;

    // ---- Q fragments (MFMA B operand), pre-scaled ----
    short8 qf[4];
    {
        const float* qp = Qg + base + (size_t)(q0w + qc) * D_HEAD + g * 8;
        #pragma unroll
        for (int db = 0; db < 4; ++db) {
            float4 x0 = *(const float4*)(qp + db * 32);
            float4 x1 = *(const float4*)(qp + db * 32 + 4);
            float tt[8] = {x0.x, x0.y, x0.z, x0.w, x1.x, x1.y, x1.z, x1.w};
            short8 f;
            #pragma unroll
            for (int j = 0; j < 8; ++j) f[j] = (short)f2bf(tt[j] * CSC);
            qf[db] = f;
        }
    }

    const int tb = b * NKVT;
    auto stage_K = [&](int t) {             // 4 DMA issues/wave
        const unsigned short* ks = Kp + (size_t)(tb + t) * TILE_SH + w * 2048 + lane * 8;
        #pragma unroll
        for (int ii = 0; ii < 4; ++ii) gld16(ks + ii * 512, &Klds[w * 2048 + ii * 512]);
    };
    auto stage_V = [&](int t) {
        const unsigned short* vs = Vp + (size_t)(tb + t) * TILE_SH + w * 2048 + lane * 8;
        #pragma unroll
        for (int ii = 0; ii < 4; ++ii) gld16(vs + ii * 512, &Vlds[w * 2048 + ii * 512]);
    };

    f32x4 o[8] = {};                        // o[db][r] = O[q=4g+r][d=db*16+qc]
    float m = -1e30f, lsum = 0.f;           // lsum lane-partial until epilogue
    const int qidx = q0w + qc;
    const int nt = hi_t - lo_t;

    stage_K(lo_t);                          // 4 outstanding (oldest)
    stage_V(lo_t);                          // +4

    for (int i = 0; i < nt; ++i) {
        const int t   = lo_t + i;
        const int kv0 = t * KVBLK;
        const bool more = (i + 1 < nt);

        // K[t] landed in every wave before anyone reads it
        wait_vm<4>();
        barrier();

        const int t16max = min(3, (q0w + 15 - kv0) >> 4);
        const int ksmax  = min(1, (q0w + 15 - kv0) >> 5);

        // ---- swapped QK^T: rows = k, cols = q ----
        f32x4 st[4] = {};
        __builtin_amdgcn_s_setprio(1);
        #pragma unroll
        for (int t16 = 0; t16 < 4; ++t16) {
            if (t16 <= t16max) {
                const int kr = t16 * 16 + qc;
                const int swz = (kr & 7) << 3;
                #pragma unroll
                for (int db = 0; db < 4; ++db) {
                    short8 kf = *(const short8*)&Klds[(kr * 128 + db * 32 + g * 8) ^ swz];
                    st[t16] = __builtin_amdgcn_mfma_f32_16x16x32_bf16(kf, qf[db], st[t16], 0, 0, 0);
                }
            }
        }
        __builtin_amdgcn_s_setprio(0);

        barrier();                           // all waves done reading Klds
        if (more) stage_K(t + 1);            // K DMA hides under softmax + PV

        float s[16];
        #pragma unroll
        for (int t16 = 0; t16 < 4; ++t16)
            #pragma unroll
            for (int r = 0; r < 4; ++r)
                s[t16*4+r] = (t16 <= t16max) ? st[t16][r] : -1e30f;

        if (kv0 + KVBLK - 1 > q0w) {         // diagonal: per-lane causal mask
            #pragma unroll
            for (int t16 = 0; t16 < 4; ++t16)
                #pragma unroll
                for (int r = 0; r < 4; ++r)
                    if (kv0 + t16 * 16 + g * 4 + r > qidx) s[t16*4+r] = -1e30f;
        }

        // ---- online softmax, defer-max; no cross-lane ops in common path ----
        float m0 = fmaxf(fmaxf(s[0],s[1]), fmaxf(s[2],s[3]));
        float m1 = fmaxf(fmaxf(s[4],s[5]), fmaxf(s[6],s[7]));
        float m2 = fmaxf(fmaxf(s[8],s[9]), fmaxf(s[10],s[11]));
        float m3 = fmaxf(fmaxf(s[12],s[13]), fmaxf(s[14],s[15]));
        float mx = fmaxf(fmaxf(m0,m1), fmaxf(m2,m3));

        if (__any(mx > m + 8.0f)) {
            mx = fmaxf(mx, __shfl_xor(mx, 16));
            mx = fmaxf(mx, __shfl_xor(mx, 32));
            float mnew = fmaxf(m, mx);
            float alpha = exp2f(m - mnew);
            m = mnew;
            lsum *= alpha;
            float a_o[4];
            #pragma unroll
            for (int r = 0; r < 4; ++r) a_o[r] = __shfl(alpha, g * 4 + r);
            #pragma unroll
            for (int db = 0; db < 8; ++db)
                #pragma unroll
                for (int r = 0; r < 4; ++r) o[db][r] *= a_o[r];
        }

        float p[16];
        #pragma unroll
        for (int ii = 0; ii < 16; ++ii) p[ii] = exp2f(s[ii] - m);
        float r0 = (p[0]+p[1]) + (p[2]+p[3]);
        float r1 = (p[4]+p[5]) + (p[6]+p[7]);
        float r2 = (p[8]+p[9]) + (p[10]+p[11]);
        float r3 = (p[12]+p[13]) + (p[14]+p[15]);
        lsum += (r0+r1) + (r2+r3);

        // V[t] landed in every wave before anyone reads it
        if (more) wait_vm<4>(); else wait_vm<0>();
        barrier();

        // ---- P -> wave-private LDS (bf16, swizzled) ----
        const int pswz = (qc & 7) << 3;
        #pragma unroll
        for (int t16 = 0; t16 < 4; ++t16) {
            uint2 u = { cvtpk(p[t16*4+0], p[t16*4+1]), cvtpk(p[t16*4+2], p[t16*4+3]) };
            *(uint2*)&Plds[w][(qc * 64 + t16 * 16 + g * 4) ^ pswz] = u;
        }

        // ---- PV ----
        __builtin_amdgcn_s_setprio(1);
        #pragma unroll
        for (int ks = 0; ks < 2; ++ks) {
            if (ks <= ksmax) {
                short8 pa = *(const short8*)&Plds[w][(qc * 64 + ks * 32 + g * 8) ^ pswz];
                #pragma unroll
                for (int db = 0; db < 8; ++db) {
                    const int d = db * 16 + qc;
                    short8 vf = *(const short8*)&Vlds[(d * 64 + ks * 32 + g * 8) ^ ((d & 7) << 3)];
                    o[db] = __builtin_amdgcn_mfma_f32_16x16x32_bf16(pa, vf, o[db], 0, 0, 0);
                }
            }
        }
        __builtin_amdgcn_s_setprio(0);

        barrier();                           // all waves done reading Vlds
        if (more) stage_V(t + 1);            // V DMA hides under next QK^T
    }

    // ---- epilogue ----
    lsum += __shfl_xor(lsum, 16);
    lsum += __shfl_xor(lsum, 32);

    if (MODE == 1 && pslot >= 0) {
        float* po = Po + (size_t)pslot * (QBLK * D_HEAD);
        #pragma unroll
        for (int db = 0; db < 8; ++db)
            #pragma unroll
            for (int r = 0; r < 4; ++r)
                po[(w * 16 + g * 4 + r) * D_HEAD + db * 16 + qc] = o[db][r];
        if (g == 0) {
            float* ml = Ml + (size_t)pslot * (QBLK * 2);
            ml[(w * 16 + qc) * 2 + 0] = m;
            ml[(w * 16 + qc) * 2 + 1] = lsum;
        }
    } else {
        float linv = 1.0f / lsum;
        float li[4];
        #pragma unroll
        for (int r = 0; r < 4; ++r) li[r] = __shfl(linv, g * 4 + r);
        #pragma unroll
        for (int db = 0; db < 8; ++db)
            #pragma unroll
            for (int r = 0; r < 4; ++r)
                Og[base + (size_t)(q0w + g * 4 + r) * D_HEAD + db * 16 + qc] = o[db][r] * li[r];
    }
}

// combine two KV-halves of each heavy q-block
__global__ __launch_bounds__(256)
void combine(const float* __restrict__ Po, const float* __restrict__ Ml,
             float* __restrict__ Og)
{
    const int hq  = blockIdx.x;             // 0..255 = (b<<4)|a
    const int tid = threadIdx.x;
    const int b   = hq >> 4;
    const int qb  = 16 + (hq & 15);
    const int row = tid >> 2;
    const int c0  = (tid & 3) * 32;

    const float* mlA = Ml + (size_t)(hq * 2 + 0) * (QBLK * 2);
    const float* mlB = Ml + (size_t)(hq * 2 + 1) * (QBLK * 2);
    const float mA = mlA[row*2], lA = mlA[row*2+1];
    const float mB = mlB[row*2], lB = mlB[row*2+1];
    const float M  = fmaxf(mA, mB);
    const float aA = exp2f(mA - M), aB = exp2f(mB - M);
    const float rdenom = 1.0f / (aA * lA + aB * lB);

    const float* pA = Po + (size_t)(hq * 2 + 0) * (QBLK * D_HEAD) + row * D_HEAD + c0;
    const float* pB = Po + (size_t)(hq * 2 + 1) * (QBLK * D_HEAD) + row * D_HEAD + c0;
    float* op = Og + (size_t)b * S_LEN * D_HEAD + (size_t)(qb * QBLK + row) * D_HEAD + c0;

    #pragma unroll
    for (int j = 0; j < 8; ++j) {
        float4 xa = *(const float4*)(pA + j * 4);
        float4 xb = *(const float4*)(pB + j * 4);
        float4 r;
        r.x = (aA*xa.x + aB*xb.x) * rdenom;
        r.y = (aA*xa.y + aB*xb.y) * rdenom;
        r.z = (aA*xa.z + aB*xb.z) * rdenom;
        r.w = (aA*xa.w + aB*xb.w) * rdenom;
        *(float4*)(op + j * 4) = r;
    }
}

extern "C" void kernel_launch(void* const* d_in, const int* in_sizes, int n_in,
                              void* d_out, int out_size, void* d_ws, size_t ws_size,
                              hipStream_t stream) {
    const float* Q = (const float*)d_in[0];
    const float* K = (const float*)d_in[1];
    const float* V = (const float*)d_in[2];
    float* O = (float*)d_out;

    const size_t tile_elems = (size_t)BATCH * NKVT * TILE_SH;
    unsigned short* Kp = (unsigned short*)d_ws;
    unsigned short* Vp = Kp + tile_elems;
    float*          Po = (float*)(Vp + tile_elems);             // 512 * 8192 floats
    float*          Mlp = Po + (size_t)512 * QBLK * D_HEAD;
    const size_t need_bytes = (char*)(Mlp + 512 * QBLK * 2) - (char*)d_ws;

    prep<<<dim3(BATCH * NKVT), dim3(256), 0, stream>>>(K, V, Kp, Vp);
    if (ws_size >= need_bytes) {
        attn_fwd<1><<<dim3(768), dim3(256), 0, stream>>>(Q, Kp, Vp, O, Po, Mlp);
        combine<<<dim3(256), dim3(256), 0, stream>>>(Po, Mlp, O);
    } else {
        attn_fwd<0><<<dim3(512), dim3(256), 0, stream>>>(Q, Kp, Vp, O, nullptr, nullptr);
    }
}